// Round 14
// baseline (178.671 us; speedup 1.0000x reference)
//
#include <hip/hip_runtime.h>
#include <hip/hip_bf16.h>

// Problem constants
#define B_  16
#define L_  512
#define D_  1024
#define H_  16
#define DH_ 64
#define NEG_ (-1e9f)
#define QB2 32
#define KB2 32
#define LDP 72    // padded LDS row (bf16) for attention K tiles

#define GK  1024  // K dim of both GEMMs
#define NT  32    // GK/32 K-tiles for the BK=32 stage-1 GEMM

typedef unsigned short ushort_t;
typedef __attribute__((ext_vector_type(8))) short bf16x8;
typedef __attribute__((ext_vector_type(4))) float f32x4;

__device__ __forceinline__ ushort_t f2bf(float f) {
    unsigned u = __float_as_uint(f);
    u += 0x7FFFu + ((u >> 16) & 1u);   // round-to-nearest-even
    return (ushort_t)(u >> 16);
}
__device__ __forceinline__ unsigned packbf(float a, float b) {
    return (unsigned)f2bf(a) | ((unsigned)f2bf(b) << 16);
}

__device__ __forceinline__ void gload_lds16(const void* g, void* l) {
    __builtin_amdgcn_global_load_lds(
        (const __attribute__((address_space(1))) void*)g,
        (__attribute__((address_space(3))) void*)l, 16, 0, 0);
}

// ---------------------------------------------------------------------------
// Merged prep: x f32->bf16  +  transpose Wqkv  +  transpose Wfc (one dispatch)
// ---------------------------------------------------------------------------
__global__ __launch_bounds__(256) void prep_all(const float* __restrict__ x,
                                                const float* __restrict__ Wqkv,
                                                const float* __restrict__ Wfc,
                                                ushort_t* __restrict__ xbf,
                                                ushort_t* __restrict__ WqT,
                                                ushort_t* __restrict__ WfT) {
    __shared__ float tile[32][33];
    const int bid = blockIdx.x;
    const int t   = threadIdx.x;

    if (bid < 8192) {   // conv x -> xbf
        const int i = (bid * 256 + t) * 4;
        const float4 v = *(const float4*)&x[i];
        ushort4 o;
        o.x = f2bf(v.x); o.y = f2bf(v.y); o.z = f2bf(v.z); o.w = f2bf(v.w);
        *(ushort4*)&xbf[i] = o;
        return;
    }
    const float* src; ushort_t* dst; int C, gx, gy;
    if (bid < 8192 + 4096) {
        const int lb = bid - 8192;
        src = Wqkv; dst = WqT; C = 4096; gx = lb & 127; gy = lb >> 7;
    } else {
        const int lb = bid - 12288;
        src = Wfc;  dst = WfT; C = 1024; gx = lb & 31;  gy = lb >> 5;
    }
    const int R  = 1024;
    const int r0 = gy * 32, c0 = gx * 32;
    const int tr = t >> 3, tc = (t & 7) * 4;
    const float4 v = *(const float4*)&src[(size_t)(r0 + tr) * C + c0 + tc];
    tile[tr][tc + 0] = v.x;
    tile[tr][tc + 1] = v.y;
    tile[tr][tc + 2] = v.z;
    tile[tr][tc + 3] = v.w;
    __syncthreads();
    ushort4 o;
    o.x = f2bf(tile[tc + 0][tr]);
    o.y = f2bf(tile[tc + 1][tr]);
    o.z = f2bf(tile[tc + 2][tr]);
    o.w = f2bf(tile[tc + 3][tr]);
    *(ushort4*)&dst[(size_t)(c0 + tr) * R + r0 + tc] = o;
}

// ---------------------------------------------------------------------------
// Stage-3 GEMM (128x128, BK=64) with row-XOR LDS swizzle (validated r9-r13).
// ---------------------------------------------------------------------------
__global__ __launch_bounds__(256) void gemm_bf16_mfma(const ushort_t* __restrict__ A,
                                                      const ushort_t* __restrict__ Bt,
                                                      const float* __restrict__ bias,
                                                      float* __restrict__ C,
                                                      int M, int N, int K) {
    __shared__ __align__(16) ushort_t As[128 * 64];
    __shared__ __align__(16) ushort_t Bs[128 * 64];

    const int t    = threadIdx.x;
    const int wave = t >> 6;
    const int lane = t & 63;
    const int m0   = blockIdx.y * 128;
    const int n0   = blockIdx.x * 128;
    const int wr   = wave >> 1;
    const int wc   = wave & 1;

    const int lrow = lane >> 3;
    const int ksl  = (lane & 7) ^ lrow;
    const int llo  = lane & 15;
    const int lhi  = lane >> 4;

    f32x4 acc[4][4] = {};

    for (int k0 = 0; k0 < K; k0 += 64) {
        #pragma unroll
        for (int i = 0; i < 4; ++i) {
            const int row = wave * 32 + i * 8;
            gload_lds16(A + (size_t)(m0 + row + lrow) * K + k0 + ksl * 8,
                        As + (size_t)row * 64);
            gload_lds16(Bt + (size_t)(n0 + row + lrow) * K + k0 + ksl * 8,
                        Bs + (size_t)row * 64);
        }
        __syncthreads();

        #pragma unroll
        for (int ks = 0; ks < 2; ++ks) {
            bf16x8 af[4], bfr[4];
            #pragma unroll
            for (int m = 0; m < 4; ++m) {
                const int row = wr * 64 + m * 16 + llo;
                af[m] = *(const bf16x8*)&As[row * 64 + (((ks * 4 + lhi) ^ (row & 7)) << 3)];
            }
            #pragma unroll
            for (int n = 0; n < 4; ++n) {
                const int row = wc * 64 + n * 16 + llo;
                bfr[n] = *(const bf16x8*)&Bs[row * 64 + (((ks * 4 + lhi) ^ (row & 7)) << 3)];
            }
            #pragma unroll
            for (int m = 0; m < 4; ++m)
                #pragma unroll
                for (int n = 0; n < 4; ++n)
                    acc[m][n] = __builtin_amdgcn_mfma_f32_16x16x32_bf16(
                        af[m], bfr[n], acc[m][n], 0, 0, 0);
        }
        __syncthreads();
    }

    #pragma unroll
    for (int m = 0; m < 4; ++m) {
        #pragma unroll
        for (int n = 0; n < 4; ++n) {
            const int col = n0 + wc * 64 + n * 16 + llo;
            const float bv = bias[col];
            #pragma unroll
            for (int i = 0; i < 4; ++i) {
                const int row = m0 + wr * 64 + m * 16 + lhi * 4 + i;
                C[(size_t)row * N + col] = acc[m][n][i] + bv;
            }
        }
    }
}

// ---------------------------------------------------------------------------
// Stage-1 GEMM: 128x128 tile, 256 threads = 4 waves (2x2), BK=32,
// 3-buffer LDS ring (48 KB -> 3 blocks/CU = 3 waves/SIMD), free-running
// 1-barrier/K-tile, 2-tile-ahead prefetch with counted vmcnt(4),
// XOR-swizzled LDS (both sides; identical lane algebra to the validated
// round-8 kernel).  Grid 2048 blocks (XCD-swizzled).
// Ring safety: buf (kt+2)%3 = buf(kt-1), last read in iter kt-1, one
// barrier before overwrite.  vmcnt(4) at tile end leaves only kt+2's 4
// loads in flight (4 gloads/thread per tile: A x2 + B x2).
// ---------------------------------------------------------------------------
__device__ __forceinline__ bf16x8 frag_ld(const ushort_t* tile, int row, int lhi) {
    const int slot = lhi ^ ((row >> 1) & 3);
    return *(const bf16x8*)&tile[row * 32 + (slot << 3)];
}

__global__ __launch_bounds__(256, 3) void gemm128_fr(const ushort_t* __restrict__ A,
                                                     const ushort_t* __restrict__ Bt,
                                                     ushort_t* __restrict__ C,
                                                     int nbn, int N) {
    extern __shared__ __align__(16) ushort_t lds[];   // 3 bufs x {A,B} x 128x32

    const int t    = threadIdx.x;
    const int wave = t >> 6;
    const int lane = t & 63;
    const int wr   = wave >> 1;       // 0..1
    const int wc   = wave & 1;        // 0..1
    const int lhi  = lane >> 4;       // 0..3
    const int llo  = lane & 15;       // 0..15
    const int srow  = lane >> 2;                       // 0..15
    const int sslot = (lane & 3) ^ ((lane >> 3) & 3);  // pre-swizzled source slot

    // XCD-aware bijective swizzle (2048 % 8 == 0)
    const int cpx = gridDim.x >> 3;
    const int swz = (blockIdx.x & 7) * cpx + (blockIdx.x >> 3);
    const int m0  = (swz / nbn) * 128;
    const int n0  = (swz % nbn) * 128;

    // stage mat (0=A,1=B) of K-tile kt into buf: 2 gloads (128 rows x 32)
    #define STAGE_T(mat, gptr, g0, kt, buf)                                        \
        _Pragma("unroll")                                                          \
        for (int j = 0; j < 2; ++j) {                                              \
            gload_lds16((gptr) + (size_t)((g0) + j * 64 + (wave << 4) + srow) * GK \
                            + (kt) * 32 + (sslot << 3),                            \
                        lds + ((buf) * 2 + (mat)) * 4096                           \
                            + (j * 64 + (wave << 4)) * 32);                        \
        }

    f32x4 acc[4][4] = {};

    STAGE_T(0, A,  m0, 0, 0); STAGE_T(1, Bt, n0, 0, 0);
    STAGE_T(0, A,  m0, 1, 1); STAGE_T(1, Bt, n0, 1, 1);
    asm volatile("s_waitcnt vmcnt(4)" ::: "memory");   // tile 0 landed, tile 1 in flight
    __builtin_amdgcn_s_barrier();

    for (int kt = 0; kt < NT; ++kt) {
        const int buf = kt % 3;
        const ushort_t* Ab = lds + (buf * 2 + 0) * 4096;
        const ushort_t* Bb = lds + (buf * 2 + 1) * 4096;

        bf16x8 afr[4], bfr[4];
        #pragma unroll
        for (int mi = 0; mi < 4; ++mi)
            afr[mi] = frag_ld(Ab, wr * 64 + mi * 16 + llo, lhi);
        #pragma unroll
        for (int n = 0; n < 4; ++n)
            bfr[n] = frag_ld(Bb, wc * 64 + n * 16 + llo, lhi);

        if (kt + 2 < NT) {
            const int nb = (kt + 2) % 3;
            STAGE_T(0, A,  m0, kt + 2, nb);
            STAGE_T(1, Bt, n0, kt + 2, nb);
        }

        __builtin_amdgcn_s_setprio(1);
        #pragma unroll
        for (int mi = 0; mi < 4; ++mi)
            #pragma unroll
            for (int n = 0; n < 4; ++n)
                acc[mi][n] = __builtin_amdgcn_mfma_f32_16x16x32_bf16(
                    afr[mi], bfr[n], acc[mi][n], 0, 0, 0);
        __builtin_amdgcn_s_setprio(0);

        if (kt + 2 < NT)      { asm volatile("s_waitcnt vmcnt(4)" ::: "memory"); }
        else if (kt + 1 < NT) { asm volatile("s_waitcnt vmcnt(0)" ::: "memory"); }
        __builtin_amdgcn_s_barrier();
    }
    #undef STAGE_T

    // epilogue: C write (bf16)
    #pragma unroll
    for (int mi = 0; mi < 4; ++mi) {
        #pragma unroll
        for (int n = 0; n < 4; ++n) {
            const int col = n0 + wc * 64 + n * 16 + llo;
            #pragma unroll
            for (int i = 0; i < 4; ++i) {
                const int row = m0 + wr * 64 + mi * 16 + lhi * 4 + i;
                C[(size_t)row * N + col] = f2bf(acc[mi][n][i]);
            }
        }
    }
}

// ---------------------------------------------------------------------------
// MFMA fused attention, swapped-operand (S^T) form, QB=KB=32, 128 threads =
// 2 waves (validated rounds 11-13, unchanged).
// ---------------------------------------------------------------------------
__global__ __launch_bounds__(128) void attn_mfma(const ushort_t* __restrict__ qkv,
                                                 const int* __restrict__ mask,
                                                 const int* __restrict__ qmask,
                                                 const float* __restrict__ shiftp,
                                                 const float* __restrict__ biasp,
                                                 const int* __restrict__ useg,
                                                 ushort_t* __restrict__ O) {
    __shared__ __align__(16) ushort_t K1s[KB2][LDP];
    __shared__ __align__(16) ushort_t K2s[KB2][LDP];
    __shared__ __align__(16) ushort_t Vt[DH_][36];     // [d][kv], kv=32 + pad
    __shared__ __align__(16) unsigned Ps32[QB2][36];   // P^T packed pairs / O out
    __shared__ __align__(16) int      Ms[L_];          // (qmask<<1)|mask per key

    const int t    = threadIdx.x;
    const int wave = t >> 6;        // 0..1
    const int lane = t & 63;
    const int lhi  = lane >> 4;     // 0..3
    const int llo  = lane & 15;     // 0..15

    // XCD-aware bijective swizzle (4096 % 8 == 0)
    const int orig = blockIdx.x;
    const int swz  = (orig & 7) * 512 + (orig >> 3);
    const int bh   = swz >> 4;            // 0..255
    const int qb   = swz & 15;            // 0..15
    const int b    = bh >> 4;
    const int h    = bh & 15;
    const int q0   = qb * QB2;

    const float shiftv = shiftp[0];
    const float biasv  = biasp[0];
    const int   useG   = useg[0];
    const size_t rowbase = (size_t)b * L_ * (4 * D_);
    const int    hoff    = h * DH_;

    // Gaussian band: contiguous surviving kt range [lo, hi] (block-uniform)
    int lo = 0, hi = (L_ / KB2) - 1;
    if (useG) {
        while (lo < hi) {
            const int k0 = lo * KB2;
            int dmin = (k0 > q0) ? (k0 - (q0 + QB2 - 1)) : (q0 - (k0 + KB2 - 1));
            if (dmin < 0) dmin = 0;
            if (shiftv * (float)dmin * (float)dmin > 240.f) ++lo; else break;
        }
        while (hi > lo) {
            const int k0 = hi * KB2;
            int dmin = (k0 > q0) ? (k0 - (q0 + QB2 - 1)) : (q0 - (k0 + KB2 - 1));
            if (dmin < 0) dmin = 0;
            if (shiftv * (float)dmin * (float)dmin > 240.f) --hi; else break;
        }
    }

    // preload key mask codes — band-limited (block-uniform range)
    for (int k = lo * KB2 + t; k < (hi + 1) * KB2; k += 128)
        Ms[k] = (qmask[b * L_ + k] << 1) | (mask[b * L_ + k] != 0 ? 1 : 0);

    // Q B-fragments straight from global (K-contiguous)
    const int gq = q0 + wave * 16 + llo;
    bf16x8 af_q[2];
    #pragma unroll
    for (int ks = 0; ks < 2; ++ks)
        af_q[ks] = *(const bf16x8*)&qkv[rowbase + (size_t)gq * (4 * D_) + hoff
                                        + ks * 32 + lhi * 8];
    const int qm_q = qmask[b * L_ + gq];

    float m_run = -1e30f, l_run = 0.f;
    f32x4 acc_o[4] = {};   // O^T frags: col=q=llo, row d = n2*16 + lhi*4 + i

    // staging index constants (128 threads)
    const int srow = t >> 2;          // 0..31 (K rows)
    const int scol = (t & 3) * 8;     // 0,8,16,24 (+32 for second chunk)
    const int vkv  = t & 31;          // V row (key)
    const int vd0  = (t >> 5) * 8;    // 0,8,16,24 (+32 for second chunk)

    uint4 pk1[2], pk2[2], pvv[2];

    #define ISSUE_KV(kt_) do {                                                          \
        const int k0_ = (kt_) * KB2;                                                    \
        _Pragma("unroll")                                                               \
        for (int it = 0; it < 2; ++it) {                                                \
            const size_t gb = rowbase + (size_t)(k0_ + srow) * (4 * D_) + hoff          \
                              + scol + it * 32;                                         \
            pk1[it] = *(const uint4*)&qkv[gb + D_];                                     \
            pk2[it] = *(const uint4*)&qkv[gb + 2 * D_];                                 \
            pvv[it] = *(const uint4*)&qkv[rowbase + (size_t)(k0_ + vkv) * (4 * D_)      \
                                          + 3 * D_ + hoff + vd0 + it * 32];             \
        }                                                                               \
    } while (0)

    ISSUE_KV(lo);

    for (int kt = lo; kt <= hi; ++kt) {
        const int k0 = kt * KB2;

        // write staged regs -> LDS
        #pragma unroll
        for (int it = 0; it < 2; ++it) {
            *(uint4*)&K1s[srow][scol + it * 32] = pk1[it];
            *(uint4*)&K2s[srow][scol + it * 32] = pk2[it];
            const int d = vd0 + it * 32;
            const uint4 raw = pvv[it];
            Vt[d + 0][vkv] = (ushort_t)(raw.x & 0xFFFFu);
            Vt[d + 1][vkv] = (ushort_t)(raw.x >> 16);
            Vt[d + 2][vkv] = (ushort_t)(raw.y & 0xFFFFu);
            Vt[d + 3][vkv] = (ushort_t)(raw.y >> 16);
            Vt[d + 4][vkv] = (ushort_t)(raw.z & 0xFFFFu);
            Vt[d + 5][vkv] = (ushort_t)(raw.z >> 16);
            Vt[d + 6][vkv] = (ushort_t)(raw.w & 0xFFFFu);
            Vt[d + 7][vkv] = (ushort_t)(raw.w >> 16);
        }
        if (kt < hi) ISSUE_KV(kt + 1);
        __syncthreads();

        // S^T = mfma(K-frag, Q-frag): rows = keys (32), cols = q
        f32x4 s1[2], s2[2];
        #pragma unroll
        for (int n = 0; n < 2; ++n) { s1[n] = (f32x4){0,0,0,0}; s2[n] = (f32x4){0,0,0,0}; }
        #pragma unroll
        for (int ks = 0; ks < 2; ++ks) {
            const int kb = ks * 32 + lhi * 8;
            #pragma unroll
            for (int n = 0; n < 2; ++n) {
                const bf16x8 bk1 = *(const bf16x8*)&K1s[n * 16 + llo][kb];
                const bf16x8 bk2 = *(const bf16x8*)&K2s[n * 16 + llo][kb];
                s1[n] = __builtin_amdgcn_mfma_f32_16x16x32_bf16(bk1, af_q[ks], s1[n], 0, 0, 0);
                s2[n] = __builtin_amdgcn_mfma_f32_16x16x32_bf16(bk2, af_q[ks], s2[n], 0, 0, 0);
            }
        }

        // select + mask + Gaussian bias; in-lane max
        float sv[2][4];
        float mx = -1e30f;
        #pragma unroll
        for (int n = 0; n < 2; ++n) {
            const int4 mc = *(const int4*)&Ms[k0 + n * 16 + lhi * 4];
            const int mci[4] = {mc.x, mc.y, mc.z, mc.w};
            #pragma unroll
            for (int i = 0; i < 4; ++i) {
                const int key = k0 + n * 16 + lhi * 4 + i;
                float x = ((mci[i] >> 1) == qm_q) ? s1[n][i] : s2[n][i];
                if (!(mci[i] & 1)) x = NEG_;
                if (useG) {
                    const float dq = (float)(gq - key);
                    x -= shiftv * dq * dq + biasv;
                }
                sv[n][i] = x;
                mx = fmaxf(mx, x);
            }
        }
        mx = fmaxf(mx, __shfl_xor(mx, 16));
        mx = fmaxf(mx, __shfl_xor(mx, 32));

        const float m_new = fmaxf(m_run, mx);
        const float scale = __expf(m_run - m_new);

        float p[2][4], ls = 0.f;
        #pragma unroll
        for (int n = 0; n < 2; ++n)
            #pragma unroll
            for (int i = 0; i < 4; ++i) {
                p[n][i] = __expf(sv[n][i] - m_new);
                ls += p[n][i];
            }
        ls += __shfl_xor(ls, 16);
        ls += __shfl_xor(ls, 32);
        l_run = l_run * scale + ls;
        m_run = m_new;

        #pragma unroll
        for (int n2 = 0; n2 < 4; ++n2) {
            acc_o[n2][0] *= scale; acc_o[n2][1] *= scale;
            acc_o[n2][2] *= scale; acc_o[n2][3] *= scale;
        }

        // P^T -> packed u32 pairs -> LDS (wave-private rows, no barrier)
        const int qrow = wave * 16 + llo;
        #pragma unroll
        for (int n = 0; n < 2; ++n) {
            uint2 w;
            w.x = packbf(p[n][0], p[n][1]);
            w.y = packbf(p[n][2], p[n][3]);
            *(uint2*)&Ps32[qrow][n * 8 + lhi * 2] = w;
        }

        // PV: O^T[d][q] += V^T[d][kv] * P^T[kv][q]   (single K=32 step)
        {
            const int kb = lhi * 8;
            const bf16x8 bp = *(const bf16x8*)&Ps32[qrow][lhi * 4];
            #pragma unroll
            for (int n2 = 0; n2 < 4; ++n2) {
                const bf16x8 av = *(const bf16x8*)&Vt[n2 * 16 + llo][kb];
                acc_o[n2] = __builtin_amdgcn_mfma_f32_16x16x32_bf16(av, bp, acc_o[n2], 0, 0, 0);
            }
        }
        __syncthreads();   // protect K/V buffers before next tile's LDS write
    }
    #undef ISSUE_KV

    // epilogue: O^T frags -> LDS (reuse Ps32, wave-private) -> coalesced out
    {
        const float inv = 1.f / l_run;
        const int qrow = wave * 16 + llo;
        #pragma unroll
        for (int n2 = 0; n2 < 4; ++n2) {
            uint2 w;
            w.x = packbf(acc_o[n2][0] * inv, acc_o[n2][1] * inv);
            w.y = packbf(acc_o[n2][2] * inv, acc_o[n2][3] * inv);
            *(uint2*)&Ps32[qrow][n2 * 8 + lhi * 2] = w;
        }
    }
    __syncthreads();
    {
        const int row = t >> 2;             // 0..31
        const int c4  = (t & 3) * 8;        // u32 col
        const uint4 a  = *(const uint4*)&Ps32[row][c4];
        const uint4 b2 = *(const uint4*)&Ps32[row][c4 + 4];
        ushort_t* dst = &O[(size_t)(b * L_ + q0 + row) * D_ + hoff + c4 * 2];
        *(uint4*)dst       = a;
        *(uint4*)(dst + 8) = b2;
    }
}

// ---------------------------------------------------------------------------
// Launch
// ---------------------------------------------------------------------------
extern "C" void kernel_launch(void* const* d_in, const int* in_sizes, int n_in,
                              void* d_out, int out_size, void* d_ws, size_t ws_size,
                              hipStream_t stream) {
    const float* x      = (const float*)d_in[0];
    const int*   mask   = (const int*)d_in[1];
    const int*   qmask  = (const int*)d_in[2];
    const float* Wqkv   = (const float*)d_in[3];
    const float* Wfc    = (const float*)d_in[4];
    const float* bfc    = (const float*)d_in[5];
    const float* shift  = (const float*)d_in[6];
    const float* bias_p = (const float*)d_in[7];
    const int*   useg   = (const int*)d_in[8];
    float*       out    = (float*)d_out;

    const int M  = B_ * L_;         // 8192
    const int N1 = 4 * D_;          // 4096

    ushort_t* qkv = (ushort_t*)d_ws;
    ushort_t* Obf = qkv + (size_t)M * N1;
    ushort_t* xbf = Obf + (size_t)M * D_;
    ushort_t* WqT = xbf + (size_t)M * D_;
    ushort_t* WfT = WqT + (size_t)N1 * D_;

    prep_all<<<dim3(8192 + 4096 + 1024), 256, 0, stream>>>(x, Wqkv, Wfc,
                                                           xbf, WqT, WfT);

    // Stage 1: qkv = x @ Wqkv — 128x128 free-running 3-buf kernel
    // grid = (8192/128)*(4096/128) = 2048 blocks; dynamic LDS = 48 KiB
    gemm128_fr<<<dim3((M / 128) * (N1 / 128)), 256, 49152, stream>>>(
        xbf, WqT, qkv, N1 / 128, N1);

    // Stage 2: fused attention (QB=KB=32, band skip + async-stage) -> Obf
    attn_mfma<<<dim3((B_ * H_) * (L_ / QB2)), 128, 0, stream>>>(qkv, mask, qmask,
                                                                shift, bias_p, useg, Obf);

    // Stage 3: out = Obf @ Wfc + bfc  (128x128 swizzled kernel: 512 blocks)
    gemm_bf16_mfma<<<dim3(D_ / 128, M / 128), 256, 0, stream>>>(
        Obf, WfT, bfc, out, M, D_, D_);
}

// Round 15
// 159.311 us; speedup vs baseline: 1.1215x; 1.1215x over previous
//
#include <hip/hip_runtime.h>
#include <hip/hip_bf16.h>

// Problem constants
#define B_  16
#define L_  512
#define D_  1024
#define H_  16
#define DH_ 64
#define NEG_ (-1e9f)
#define QB2 32
#define KB2 32
#define LDP 72    // padded LDS row (bf16) for attention K tiles

#define GK  1024  // K dim of both GEMMs
#define NT  32    // GK/32 K-tiles for the BK=32 stage-1 GEMM

typedef unsigned short ushort_t;
typedef __attribute__((ext_vector_type(8))) short bf16x8;
typedef __attribute__((ext_vector_type(4))) float f32x4;

__device__ __forceinline__ ushort_t f2bf(float f) {
    unsigned u = __float_as_uint(f);
    u += 0x7FFFu + ((u >> 16) & 1u);   // round-to-nearest-even
    return (ushort_t)(u >> 16);
}
__device__ __forceinline__ unsigned packbf(float a, float b) {
    return (unsigned)f2bf(a) | ((unsigned)f2bf(b) << 16);
}

__device__ __forceinline__ void gload_lds16(const void* g, void* l) {
    __builtin_amdgcn_global_load_lds(
        (const __attribute__((address_space(1))) void*)g,
        (__attribute__((address_space(3))) void*)l, 16, 0, 0);
}

// ---------------------------------------------------------------------------
// Merged prep: x f32->bf16  +  transpose Wqkv  +  transpose Wfc (one dispatch)
// ---------------------------------------------------------------------------
__global__ __launch_bounds__(256) void prep_all(const float* __restrict__ x,
                                                const float* __restrict__ Wqkv,
                                                const float* __restrict__ Wfc,
                                                ushort_t* __restrict__ xbf,
                                                ushort_t* __restrict__ WqT,
                                                ushort_t* __restrict__ WfT) {
    __shared__ float tile[32][33];
    const int bid = blockIdx.x;
    const int t   = threadIdx.x;

    if (bid < 8192) {   // conv x -> xbf
        const int i = (bid * 256 + t) * 4;
        const float4 v = *(const float4*)&x[i];
        ushort4 o;
        o.x = f2bf(v.x); o.y = f2bf(v.y); o.z = f2bf(v.z); o.w = f2bf(v.w);
        *(ushort4*)&xbf[i] = o;
        return;
    }
    const float* src; ushort_t* dst; int C, gx, gy;
    if (bid < 8192 + 4096) {
        const int lb = bid - 8192;
        src = Wqkv; dst = WqT; C = 4096; gx = lb & 127; gy = lb >> 7;
    } else {
        const int lb = bid - 12288;
        src = Wfc;  dst = WfT; C = 1024; gx = lb & 31;  gy = lb >> 5;
    }
    const int R  = 1024;
    const int r0 = gy * 32, c0 = gx * 32;
    const int tr = t >> 3, tc = (t & 7) * 4;
    const float4 v = *(const float4*)&src[(size_t)(r0 + tr) * C + c0 + tc];
    tile[tr][tc + 0] = v.x;
    tile[tr][tc + 1] = v.y;
    tile[tr][tc + 2] = v.z;
    tile[tr][tc + 3] = v.w;
    __syncthreads();
    ushort4 o;
    o.x = f2bf(tile[tc + 0][tr]);
    o.y = f2bf(tile[tc + 1][tr]);
    o.z = f2bf(tile[tc + 2][tr]);
    o.w = f2bf(tile[tc + 3][tr]);
    *(ushort4*)&dst[(size_t)(c0 + tr) * R + r0 + tc] = o;
}

// ---------------------------------------------------------------------------
// Stage-3 GEMM (128x128, BK=64) with row-XOR LDS swizzle (validated r9-r14).
// ---------------------------------------------------------------------------
__global__ __launch_bounds__(256) void gemm_bf16_mfma(const ushort_t* __restrict__ A,
                                                      const ushort_t* __restrict__ Bt,
                                                      const float* __restrict__ bias,
                                                      float* __restrict__ C,
                                                      int M, int N, int K) {
    __shared__ __align__(16) ushort_t As[128 * 64];
    __shared__ __align__(16) ushort_t Bs[128 * 64];

    const int t    = threadIdx.x;
    const int wave = t >> 6;
    const int lane = t & 63;
    const int m0   = blockIdx.y * 128;
    const int n0   = blockIdx.x * 128;
    const int wr   = wave >> 1;
    const int wc   = wave & 1;

    const int lrow = lane >> 3;
    const int ksl  = (lane & 7) ^ lrow;
    const int llo  = lane & 15;
    const int lhi  = lane >> 4;

    f32x4 acc[4][4] = {};

    for (int k0 = 0; k0 < K; k0 += 64) {
        #pragma unroll
        for (int i = 0; i < 4; ++i) {
            const int row = wave * 32 + i * 8;
            gload_lds16(A + (size_t)(m0 + row + lrow) * K + k0 + ksl * 8,
                        As + (size_t)row * 64);
            gload_lds16(Bt + (size_t)(n0 + row + lrow) * K + k0 + ksl * 8,
                        Bs + (size_t)row * 64);
        }
        __syncthreads();

        #pragma unroll
        for (int ks = 0; ks < 2; ++ks) {
            bf16x8 af[4], bfr[4];
            #pragma unroll
            for (int m = 0; m < 4; ++m) {
                const int row = wr * 64 + m * 16 + llo;
                af[m] = *(const bf16x8*)&As[row * 64 + (((ks * 4 + lhi) ^ (row & 7)) << 3)];
            }
            #pragma unroll
            for (int n = 0; n < 4; ++n) {
                const int row = wc * 64 + n * 16 + llo;
                bfr[n] = *(const bf16x8*)&Bs[row * 64 + (((ks * 4 + lhi) ^ (row & 7)) << 3)];
            }
            #pragma unroll
            for (int m = 0; m < 4; ++m)
                #pragma unroll
                for (int n = 0; n < 4; ++n)
                    acc[m][n] = __builtin_amdgcn_mfma_f32_16x16x32_bf16(
                        af[m], bfr[n], acc[m][n], 0, 0, 0);
        }
        __syncthreads();
    }

    #pragma unroll
    for (int m = 0; m < 4; ++m) {
        #pragma unroll
        for (int n = 0; n < 4; ++n) {
            const int col = n0 + wc * 64 + n * 16 + llo;
            const float bv = bias[col];
            #pragma unroll
            for (int i = 0; i < 4; ++i) {
                const int row = m0 + wr * 64 + m * 16 + lhi * 4 + i;
                C[(size_t)row * N + col] = acc[m][n][i] + bv;
            }
        }
    }
}

// ---------------------------------------------------------------------------
// Stage-1 GEMM: round-8 free-running 256x256 kernel with prefetch depth 3.
// BK=32, 512 threads = 8 waves, 4 LDS buffers, counted vmcnt(8) steady state
// (kt+2's 4 + kt+3's 4 in flight; kt+1 landed), ONE barrier per K-tile,
// XOR-swizzled LDS (both sides), 16x16x32 MFMA.
// Ring safety (depth 3): buf (kt+3)&3 = buf(kt-1), whose reads completed
// before the barrier ending iteration kt-1, which precedes the issue in kt.
// Latency: 3 tile-times ~930 cyc >= ~900 cyc HBM latency (m126).
// ---------------------------------------------------------------------------
__device__ __forceinline__ bf16x8 frag_ld(const ushort_t* tile, int row, int lhi) {
    const int slot = lhi ^ ((row >> 1) & 3);
    return *(const bf16x8*)&tile[row * 32 + (slot << 3)];
}

__global__ __launch_bounds__(512, 2) void gemm256_8p(const ushort_t* __restrict__ A,
                                                     const ushort_t* __restrict__ Bt,
                                                     ushort_t* __restrict__ C,
                                                     int nbn, int N) {
    extern __shared__ __align__(16) ushort_t lds[];   // 4 bufs x {A,B} x 256x32

    const int t    = threadIdx.x;
    const int wave = t >> 6;
    const int lane = t & 63;
    const int wr   = wave >> 2;       // 0..1
    const int wc   = wave & 3;        // 0..3
    const int lhi  = lane >> 4;       // 0..3
    const int llo  = lane & 15;       // 0..15
    const int srow  = lane >> 2;                       // 0..15
    const int sslot = (lane & 3) ^ ((lane >> 3) & 3);  // pre-swizzled source slot

    // XCD-aware bijective swizzle (grid % 8 == 0)
    const int cpx = gridDim.x >> 3;
    const int swz = (blockIdx.x & 7) * cpx + (blockIdx.x >> 3);
    const int m0  = (swz / nbn) * 256;
    const int n0  = (swz % nbn) * 256;

    #define STAGE_H(mat, gptr, grow0, kt, half)                                         \
        gload_lds16((gptr) + (size_t)((grow0) + (half) * 128 + (wave << 4) + srow) * GK \
                        + (kt) * 32 + (sslot << 3),                                     \
                    lds + ((((kt) & 3) * 2 + (mat)) * 8192                              \
                           + ((half) * 128 + (wave << 4)) * 32))

    f32x4 acc[8][4] = {};

    // prologue: stage tiles 0,1,2 (FIFO, 12 loads/thread-group)
    STAGE_H(0, A,  m0, 0, 0); STAGE_H(0, A,  m0, 0, 1);
    STAGE_H(1, Bt, n0, 0, 0); STAGE_H(1, Bt, n0, 0, 1);
    STAGE_H(0, A,  m0, 1, 0); STAGE_H(0, A,  m0, 1, 1);
    STAGE_H(1, Bt, n0, 1, 0); STAGE_H(1, Bt, n0, 1, 1);
    STAGE_H(0, A,  m0, 2, 0); STAGE_H(0, A,  m0, 2, 1);
    STAGE_H(1, Bt, n0, 2, 0); STAGE_H(1, Bt, n0, 2, 1);
    asm volatile("s_waitcnt vmcnt(8)" ::: "memory");   // tile 0 landed; 1,2 in flight
    __builtin_amdgcn_s_barrier();

    for (int kt = 0; kt < NT; ++kt) {
        const ushort_t* At  = lds + ((kt & 3) * 2 + 0) * 8192;
        const ushort_t* Bti = lds + ((kt & 3) * 2 + 1) * 8192;

        bf16x8 afr[4], bfr[4];

        #pragma unroll
        for (int n = 0; n < 4; ++n)
            bfr[n] = frag_ld(Bti, wc * 64 + n * 16 + llo, lhi);
        #pragma unroll
        for (int mi = 0; mi < 4; ++mi)
            afr[mi] = frag_ld(At, wr * 128 + mi * 16 + llo, lhi);
        if (kt + 3 < NT) {
            STAGE_H(0, A, m0, kt + 3, 0);
            STAGE_H(0, A, m0, kt + 3, 1);
        }
        __builtin_amdgcn_s_setprio(1);
        #pragma unroll
        for (int mi = 0; mi < 4; ++mi)
            #pragma unroll
            for (int n = 0; n < 4; ++n)
                acc[mi][n] = __builtin_amdgcn_mfma_f32_16x16x32_bf16(
                    afr[mi], bfr[n], acc[mi][n], 0, 0, 0);
        __builtin_amdgcn_s_setprio(0);

        #pragma unroll
        for (int mi = 0; mi < 4; ++mi)
            afr[mi] = frag_ld(At, wr * 128 + (mi + 4) * 16 + llo, lhi);
        if (kt + 3 < NT) {
            STAGE_H(1, Bt, n0, kt + 3, 0);
            STAGE_H(1, Bt, n0, kt + 3, 1);
        }
        __builtin_amdgcn_s_setprio(1);
        #pragma unroll
        for (int mi = 0; mi < 4; ++mi)
            #pragma unroll
            for (int n = 0; n < 4; ++n)
                acc[mi + 4][n] = __builtin_amdgcn_mfma_f32_16x16x32_bf16(
                    afr[mi], bfr[n], acc[mi + 4][n], 0, 0, 0);
        __builtin_amdgcn_s_setprio(0);

        // drain so tile kt+1 is landed; keep kt+2 (and kt+3 if staged) in flight
        if (kt + 3 < NT)      { asm volatile("s_waitcnt vmcnt(8)" ::: "memory"); }
        else if (kt + 2 < NT) { asm volatile("s_waitcnt vmcnt(4)" ::: "memory"); }
        else if (kt + 1 < NT) { asm volatile("s_waitcnt vmcnt(0)" ::: "memory"); }
        __builtin_amdgcn_s_barrier();
    }
    #undef STAGE_H

    #pragma unroll
    for (int mi = 0; mi < 8; ++mi) {
        #pragma unroll
        for (int n = 0; n < 4; ++n) {
            const int col = n0 + wc * 64 + n * 16 + llo;
            #pragma unroll
            for (int i = 0; i < 4; ++i) {
                const int row = m0 + wr * 128 + mi * 16 + lhi * 4 + i;
                C[(size_t)row * N + col] = f2bf(acc[mi][n][i]);
            }
        }
    }
}

// ---------------------------------------------------------------------------
// MFMA fused attention, swapped-operand (S^T) form, QB=KB=32, 128 threads =
// 2 waves (validated rounds 11-13, unchanged).
// ---------------------------------------------------------------------------
__global__ __launch_bounds__(128) void attn_mfma(const ushort_t* __restrict__ qkv,
                                                 const int* __restrict__ mask,
                                                 const int* __restrict__ qmask,
                                                 const float* __restrict__ shiftp,
                                                 const float* __restrict__ biasp,
                                                 const int* __restrict__ useg,
                                                 ushort_t* __restrict__ O) {
    __shared__ __align__(16) ushort_t K1s[KB2][LDP];
    __shared__ __align__(16) ushort_t K2s[KB2][LDP];
    __shared__ __align__(16) ushort_t Vt[DH_][36];     // [d][kv], kv=32 + pad
    __shared__ __align__(16) unsigned Ps32[QB2][36];   // P^T packed pairs / O out
    __shared__ __align__(16) int      Ms[L_];          // (qmask<<1)|mask per key

    const int t    = threadIdx.x;
    const int wave = t >> 6;        // 0..1
    const int lane = t & 63;
    const int lhi  = lane >> 4;     // 0..3
    const int llo  = lane & 15;     // 0..15

    // XCD-aware bijective swizzle (4096 % 8 == 0)
    const int orig = blockIdx.x;
    const int swz  = (orig & 7) * 512 + (orig >> 3);
    const int bh   = swz >> 4;            // 0..255
    const int qb   = swz & 15;            // 0..15
    const int b    = bh >> 4;
    const int h    = bh & 15;
    const int q0   = qb * QB2;

    const float shiftv = shiftp[0];
    const float biasv  = biasp[0];
    const int   useG   = useg[0];
    const size_t rowbase = (size_t)b * L_ * (4 * D_);
    const int    hoff    = h * DH_;

    // Gaussian band: contiguous surviving kt range [lo, hi] (block-uniform)
    int lo = 0, hi = (L_ / KB2) - 1;
    if (useG) {
        while (lo < hi) {
            const int k0 = lo * KB2;
            int dmin = (k0 > q0) ? (k0 - (q0 + QB2 - 1)) : (q0 - (k0 + KB2 - 1));
            if (dmin < 0) dmin = 0;
            if (shiftv * (float)dmin * (float)dmin > 240.f) ++lo; else break;
        }
        while (hi > lo) {
            const int k0 = hi * KB2;
            int dmin = (k0 > q0) ? (k0 - (q0 + QB2 - 1)) : (q0 - (k0 + KB2 - 1));
            if (dmin < 0) dmin = 0;
            if (shiftv * (float)dmin * (float)dmin > 240.f) --hi; else break;
        }
    }

    // preload key mask codes — band-limited (block-uniform range)
    for (int k = lo * KB2 + t; k < (hi + 1) * KB2; k += 128)
        Ms[k] = (qmask[b * L_ + k] << 1) | (mask[b * L_ + k] != 0 ? 1 : 0);

    // Q B-fragments straight from global (K-contiguous)
    const int gq = q0 + wave * 16 + llo;
    bf16x8 af_q[2];
    #pragma unroll
    for (int ks = 0; ks < 2; ++ks)
        af_q[ks] = *(const bf16x8*)&qkv[rowbase + (size_t)gq * (4 * D_) + hoff
                                        + ks * 32 + lhi * 8];
    const int qm_q = qmask[b * L_ + gq];

    float m_run = -1e30f, l_run = 0.f;
    f32x4 acc_o[4] = {};   // O^T frags: col=q=llo, row d = n2*16 + lhi*4 + i

    // staging index constants (128 threads)
    const int srow = t >> 2;          // 0..31 (K rows)
    const int scol = (t & 3) * 8;     // 0,8,16,24 (+32 for second chunk)
    const int vkv  = t & 31;          // V row (key)
    const int vd0  = (t >> 5) * 8;    // 0,8,16,24 (+32 for second chunk)

    uint4 pk1[2], pk2[2], pvv[2];

    #define ISSUE_KV(kt_) do {                                                          \
        const int k0_ = (kt_) * KB2;                                                    \
        _Pragma("unroll")                                                               \
        for (int it = 0; it < 2; ++it) {                                                \
            const size_t gb = rowbase + (size_t)(k0_ + srow) * (4 * D_) + hoff          \
                              + scol + it * 32;                                         \
            pk1[it] = *(const uint4*)&qkv[gb + D_];                                     \
            pk2[it] = *(const uint4*)&qkv[gb + 2 * D_];                                 \
            pvv[it] = *(const uint4*)&qkv[rowbase + (size_t)(k0_ + vkv) * (4 * D_)      \
                                          + 3 * D_ + hoff + vd0 + it * 32];             \
        }                                                                               \
    } while (0)

    ISSUE_KV(lo);

    for (int kt = lo; kt <= hi; ++kt) {
        const int k0 = kt * KB2;

        // write staged regs -> LDS
        #pragma unroll
        for (int it = 0; it < 2; ++it) {
            *(uint4*)&K1s[srow][scol + it * 32] = pk1[it];
            *(uint4*)&K2s[srow][scol + it * 32] = pk2[it];
            const int d = vd0 + it * 32;
            const uint4 raw = pvv[it];
            Vt[d + 0][vkv] = (ushort_t)(raw.x & 0xFFFFu);
            Vt[d + 1][vkv] = (ushort_t)(raw.x >> 16);
            Vt[d + 2][vkv] = (ushort_t)(raw.y & 0xFFFFu);
            Vt[d + 3][vkv] = (ushort_t)(raw.y >> 16);
            Vt[d + 4][vkv] = (ushort_t)(raw.z & 0xFFFFu);
            Vt[d + 5][vkv] = (ushort_t)(raw.z >> 16);
            Vt[d + 6][vkv] = (ushort_t)(raw.w & 0xFFFFu);
            Vt[d + 7][vkv] = (ushort_t)(raw.w >> 16);
        }
        if (kt < hi) ISSUE_KV(kt + 1);
        __syncthreads();

        // S^T = mfma(K-frag, Q-frag): rows = keys (32), cols = q
        f32x4 s1[2], s2[2];
        #pragma unroll
        for (int n = 0; n < 2; ++n) { s1[n] = (f32x4){0,0,0,0}; s2[n] = (f32x4){0,0,0,0}; }
        #pragma unroll
        for (int ks = 0; ks < 2; ++ks) {
            const int kb = ks * 32 + lhi * 8;
            #pragma unroll
            for (int n = 0; n < 2; ++n) {
                const bf16x8 bk1 = *(const bf16x8*)&K1s[n * 16 + llo][kb];
                const bf16x8 bk2 = *(const bf16x8*)&K2s[n * 16 + llo][kb];
                s1[n] = __builtin_amdgcn_mfma_f32_16x16x32_bf16(bk1, af_q[ks], s1[n], 0, 0, 0);
                s2[n] = __builtin_amdgcn_mfma_f32_16x16x32_bf16(bk2, af_q[ks], s2[n], 0, 0, 0);
            }
        }

        // select + mask + Gaussian bias; in-lane max
        float sv[2][4];
        float mx = -1e30f;
        #pragma unroll
        for (int n = 0; n < 2; ++n) {
            const int4 mc = *(const int4*)&Ms[k0 + n * 16 + lhi * 4];
            const int mci[4] = {mc.x, mc.y, mc.z, mc.w};
            #pragma unroll
            for (int i = 0; i < 4; ++i) {
                const int key = k0 + n * 16 + lhi * 4 + i;
                float x = ((mci[i] >> 1) == qm_q) ? s1[n][i] : s2[n][i];
                if (!(mci[i] & 1)) x = NEG_;
                if (useG) {
                    const float dq = (float)(gq - key);
                    x -= shiftv * dq * dq + biasv;
                }
                sv[n][i] = x;
                mx = fmaxf(mx, x);
            }
        }
        mx = fmaxf(mx, __shfl_xor(mx, 16));
        mx = fmaxf(mx, __shfl_xor(mx, 32));

        const float m_new = fmaxf(m_run, mx);
        const float scale = __expf(m_run - m_new);

        float p[2][4], ls = 0.f;
        #pragma unroll
        for (int n = 0; n < 2; ++n)
            #pragma unroll
            for (int i = 0; i < 4; ++i) {
                p[n][i] = __expf(sv[n][i] - m_new);
                ls += p[n][i];
            }
        ls += __shfl_xor(ls, 16);
        ls += __shfl_xor(ls, 32);
        l_run = l_run * scale + ls;
        m_run = m_new;

        #pragma unroll
        for (int n2 = 0; n2 < 4; ++n2) {
            acc_o[n2][0] *= scale; acc_o[n2][1] *= scale;
            acc_o[n2][2] *= scale; acc_o[n2][3] *= scale;
        }

        // P^T -> packed u32 pairs -> LDS (wave-private rows, no barrier)
        const int qrow = wave * 16 + llo;
        #pragma unroll
        for (int n = 0; n < 2; ++n) {
            uint2 w;
            w.x = packbf(p[n][0], p[n][1]);
            w.y = packbf(p[n][2], p[n][3]);
            *(uint2*)&Ps32[qrow][n * 8 + lhi * 2] = w;
        }

        // PV: O^T[d][q] += V^T[d][kv] * P^T[kv][q]   (single K=32 step)
        {
            const int kb = lhi * 8;
            const bf16x8 bp = *(const bf16x8*)&Ps32[qrow][lhi * 4];
            #pragma unroll
            for (int n2 = 0; n2 < 4; ++n2) {
                const bf16x8 av = *(const bf16x8*)&Vt[n2 * 16 + llo][kb];
                acc_o[n2] = __builtin_amdgcn_mfma_f32_16x16x32_bf16(av, bp, acc_o[n2], 0, 0, 0);
            }
        }
        __syncthreads();   // protect K/V buffers before next tile's LDS write
    }
    #undef ISSUE_KV

    // epilogue: O^T frags -> LDS (reuse Ps32, wave-private) -> coalesced out
    {
        const float inv = 1.f / l_run;
        const int qrow = wave * 16 + llo;
        #pragma unroll
        for (int n2 = 0; n2 < 4; ++n2) {
            uint2 w;
            w.x = packbf(acc_o[n2][0] * inv, acc_o[n2][1] * inv);
            w.y = packbf(acc_o[n2][2] * inv, acc_o[n2][3] * inv);
            *(uint2*)&Ps32[qrow][n2 * 8 + lhi * 2] = w;
        }
    }
    __syncthreads();
    {
        const int row = t >> 2;             // 0..31
        const int c4  = (t & 3) * 8;        // u32 col
        const uint4 a  = *(const uint4*)&Ps32[row][c4];
        const uint4 b2 = *(const uint4*)&Ps32[row][c4 + 4];
        ushort_t* dst = &O[(size_t)(b * L_ + q0 + row) * D_ + hoff + c4 * 2];
        *(uint4*)dst       = a;
        *(uint4*)(dst + 8) = b2;
    }
}

// ---------------------------------------------------------------------------
// Launch
// ---------------------------------------------------------------------------
extern "C" void kernel_launch(void* const* d_in, const int* in_sizes, int n_in,
                              void* d_out, int out_size, void* d_ws, size_t ws_size,
                              hipStream_t stream) {
    const float* x      = (const float*)d_in[0];
    const int*   mask   = (const int*)d_in[1];
    const int*   qmask  = (const int*)d_in[2];
    const float* Wqkv   = (const float*)d_in[3];
    const float* Wfc    = (const float*)d_in[4];
    const float* bfc    = (const float*)d_in[5];
    const float* shift  = (const float*)d_in[6];
    const float* bias_p = (const float*)d_in[7];
    const int*   useg   = (const int*)d_in[8];
    float*       out    = (float*)d_out;

    const int M  = B_ * L_;         // 8192
    const int N1 = 4 * D_;          // 4096

    ushort_t* qkv = (ushort_t*)d_ws;
    ushort_t* Obf = qkv + (size_t)M * N1;
    ushort_t* xbf = Obf + (size_t)M * D_;
    ushort_t* WqT = xbf + (size_t)M * D_;
    ushort_t* WfT = WqT + (size_t)N1 * D_;

    prep_all<<<dim3(8192 + 4096 + 1024), 256, 0, stream>>>(x, Wqkv, Wfc,
                                                           xbf, WqT, WfT);

    // Stage 1: qkv = x @ Wqkv — 256x256 free-running kernel, prefetch depth 3
    gemm256_8p<<<dim3((M / 256) * (N1 / 256)), 512, 131072, stream>>>(
        xbf, WqT, qkv, N1 / 256, N1);

    // Stage 2: fused attention (QB=KB=32, band skip + async-stage) -> Obf
    attn_mfma<<<dim3((B_ * H_) * (L_ / QB2)), 128, 0, stream>>>(qkv, mask, qmask,
                                                                shift, bias_p, useg, Obf);

    // Stage 3: out = Obf @ Wfc + bfc  (128x128 swizzled kernel: 512 blocks)
    gemm_bf16_mfma<<<dim3(D_ / 128, M / 128), 256, 0, stream>>>(
        Obf, WfT, bfc, out, M, D_, D_);
}